// Round 6
// baseline (151.707 us; speedup 1.0000x reference)
//
#include <hip/hip_runtime.h>
#include <math.h>

#define T_STEPS 32
#define BATCH 64

// ws layout (floats)
#define WS_WXQ 0        // [8][512]
#define WS_WHQ 4096     // [8][512]
#define WS_BQ  8192     // [8]
#define WS_U   8208     // 128 matrices * 8 floats (id = wv*32 + gl*16 + d*8 + w)
#define WS_AB  25616    // 8 combos * (A 256 cplx + B 256 cplx) = 8*1024 floats

typedef float v2f __attribute__((ext_vector_type(2)));
typedef unsigned int u32x2 __attribute__((ext_vector_type(2)));
typedef __fp16 half2v __attribute__((ext_vector_type(2)));
typedef __fp16 half4v __attribute__((ext_vector_type(4)));
typedef float f32x4 __attribute__((ext_vector_type(4)));

struct c32 { float x, y; };
__device__ __forceinline__ c32 cmul(c32 a, c32 b){ return {a.x*b.x - a.y*b.y, a.x*b.y + a.y*b.x}; }
__device__ __forceinline__ c32 cadd(c32 a, c32 b){ return {a.x+b.x, a.y+b.y}; }

__device__ __forceinline__ v2f mkv(float x, float y){ v2f r; r.x = x; r.y = y; return r; }
__device__ __forceinline__ v2f cmulv(v2f a, v2f b){
    return mkv(a.x, a.x) * b + mkv(-a.y, a.y) * mkv(b.y, b.x);
}
__device__ __forceinline__ float fast_sigmoid(float x){ return 1.f/(1.f + __expf(-x)); }
__device__ __forceinline__ float fast_tanh(float x){ float e = __expf(2.f*x); return 1.f - 2.f/(e+1.f); }

__device__ __forceinline__ half4v pk4(float a, float b, float c, float d){
#if __has_builtin(__builtin_amdgcn_cvt_pkrtz)
    half2v lo = __builtin_amdgcn_cvt_pkrtz(a, b);
    half2v hi = __builtin_amdgcn_cvt_pkrtz(c, d);
    return __builtin_shufflevector(lo, hi, 0, 1, 2, 3);
#else
    half4v r; r[0] = (__fp16)a; r[1] = (__fp16)b; r[2] = (__fp16)c; r[3] = (__fp16)d;
    return r;
#endif
}

template<int C> __device__ __forceinline__ float dppf(float v){
    return __int_as_float(__builtin_amdgcn_mov_dpp(__float_as_int(v), C, 0xF, 0xF, true));
}
__device__ __forceinline__ float swap16(float v, int lane){
#if __has_builtin(__builtin_amdgcn_permlane16_swap)
    u32x2 r = __builtin_amdgcn_permlane16_swap(__float_as_uint(v), __float_as_uint(v), false, false);
    return __uint_as_float((lane & 16) ? r.x : r.y);
#else
    return __shfl_xor(v, 16);
#endif
}
__device__ __forceinline__ float swap32(float v, int lane){
#if __has_builtin(__builtin_amdgcn_permlane32_swap)
    u32x2 r = __builtin_amdgcn_permlane32_swap(__float_as_uint(v), __float_as_uint(v), false, false);
    return __uint_as_float((lane & 32) ? r.x : r.y);
#else
    return __shfl_xor(v, 32);
#endif
}
template<int LM> __device__ __forceinline__ float lanexor(float v, int lane){
    if constexpr (LM == 1)       return dppf<0xB1>(v);
    else if constexpr (LM == 2)  return dppf<0x4E>(v);
    else if constexpr (LM == 4)  return dppf<0x1B>(dppf<0x141>(v));
    else if constexpr (LM == 8)  return dppf<0x128>(v);
    else if constexpr (LM == 16) return swap16(v, lane);
    else                         return swap32(v, lane);
}
__device__ __forceinline__ float rdl(float v, int l){
    return __int_as_float(__builtin_amdgcn_readlane(__float_as_int(v), l));
}
__device__ __forceinline__ void fsincos(float rev, float* s, float* c){
#if __has_builtin(__builtin_amdgcn_sinf) && __has_builtin(__builtin_amdgcn_cosf)
    *s = __builtin_amdgcn_sinf(rev);
    *c = __builtin_amdgcn_cosf(rev);
#else
    __sincosf(rev * 6.2831853071795864f, s, c);
#endif
}

__device__ __forceinline__ void rot_u(const float* p3, float* dst){
    float a = 0.5f * p3[0], b = 0.5f * p3[1], c = 0.5f * p3[2];
    float ca = cosf(a), sa = sinf(a);
    float cb = cosf(b), sb = sinf(b);
    float cc = cosf(c), sc = sinf(c);
    c32 eb  = {cb, -sb};
    c32 ebc = {cb,  sb};
    c32 scx = {0.f, -sc};
    c32 m00 = { eb.x * ca,  eb.y * ca};
    c32 m01 = {-eb.x * sa, -eb.y * sa};
    c32 m10 = { ebc.x * sa, ebc.y * sa};
    c32 m11 = { ebc.x * ca, ebc.y * ca};
    c32 U00 = cadd(c32{cc * m00.x, cc * m00.y}, cmul(scx, m10));
    c32 U01 = cadd(c32{cc * m01.x, cc * m01.y}, cmul(scx, m11));
    c32 U10 = cadd(cmul(scx, m00), c32{cc * m10.x, cc * m10.y});
    c32 U11 = cadd(cmul(scx, m01), c32{cc * m11.x, cc * m11.y});
    dst[0] = U00.x; dst[1] = U00.y; dst[2] = U01.x; dst[3] = U01.y;
    dst[4] = U10.x; dst[5] = U10.y; dst[6] = U11.x; dst[7] = U11.y;
}

// blocks 0..31: Wxq/Whq fold; block 32: U matrices; blocks 33..40: Kronecker A/B
__global__ void precompute_kernel(const float* __restrict__ W_proj,
                                  const float* __restrict__ b_proj,
                                  const float* __restrict__ W_toq,
                                  const float* __restrict__ fP, const float* __restrict__ iP,
                                  const float* __restrict__ gP, const float* __restrict__ oP,
                                  float* __restrict__ ws)
{
    int tid = threadIdx.x;
    int blk = blockIdx.x;
    if (blk < 32) {
        int idx = blk * 256 + tid;
        int q = idx >> 10, dd = idx & 1023;
        float acc = 0.f;
        for (int p = 0; p < 64; ++p) acc += W_toq[q * 64 + p] * W_proj[p * 1024 + dd];
        if (dd < 512) ws[WS_WXQ + q * 512 + dd] = acc;
        else          ws[WS_WHQ + q * 512 + (dd - 512)] = acc;
        if (idx < 8) {
            float a2 = 0.f;
            for (int p = 0; p < 64; ++p) a2 += W_toq[idx * 64 + p] * b_proj[p];
            ws[WS_BQ + idx] = a2;
        }
    } else if (blk == 32) {
        if (tid < 128) {
            int gt = tid >> 5, rest = tid & 31;
            const float* P = (gt == 0) ? fP : (gt == 1) ? iP : (gt == 2) ? gP : oP;
            int g = (rest >> 4) & 1, d = (rest >> 3) & 1, w = rest & 7;
            rot_u(P + (((g * 2 + d) * 8 + w) * 3), ws + WS_U + tid * 8);
        }
    } else {
        // Kronecker pair matrices for combo = (gt*2+gl)
        __shared__ float sW[8][8];
        int combo = blk - 33;
        int gt = combo >> 1, gl = combo & 1;
        if (tid < 8) {
            const float* P = (gt == 0) ? fP : (gt == 1) ? iP : (gt == 2) ? gP : oP;
            rot_u(P + (((gl * 2 + 1) * 8 + tid) * 3), &sW[tid][0]);  // d=1, wire tid
        }
        __syncthreads();
        int rp = tid >> 4, rr = tid & 15;
        c32 pa = {1.f, 0.f};
        #pragma unroll
        for (int w = 0; w < 4; ++w) {
            int i = (rp >> (3 - w)) & 1, j = (rr >> (3 - w)) & 1;
            c32 e = {sW[w][(i * 2 + j) * 2], sW[w][(i * 2 + j) * 2 + 1]};
            pa = cmul(pa, e);
        }
        ws[WS_AB + combo * 1024 + tid * 2]     = pa.x;
        ws[WS_AB + combo * 1024 + tid * 2 + 1] = pa.y;
        c32 pb = {1.f, 0.f};
        #pragma unroll
        for (int w = 4; w < 8; ++w) {
            int i = (rp >> (7 - w)) & 1, j = (rr >> (7 - w)) & 1;
            c32 e = {sW[w][(i * 2 + j) * 2], sW[w][(i * 2 + j) * 2 + 1]};
            pb = cmul(pb, e);
        }
        ws[WS_AB + combo * 1024 + 512 + tid * 2]     = pb.x;
        ws[WS_AB + combo * 1024 + 512 + tid * 2 + 1] = pb.y;
    }
}

__global__ __launch_bounds__(256, 1)
void recurrence_kernel(const float* __restrict__ inputs,
                       const float* __restrict__ W_q2h,
                       const float* __restrict__ ws,
                       float* __restrict__ out)
{
    __shared__ __align__(16) float sU[1024];
    __shared__ __align__(16) float sXq[T_STEPS * 8];
    __shared__ __align__(16) float sexpW[4][8];
    __shared__ __align__(16) float qpartS[2][8];   // parity double-buffer, ds_add accumulated

    int tid = threadIdx.x;   // 256
    int b   = blockIdx.x;    // 64
    int wv  = tid >> 6;
    int lane = tid & 63;
    int l = lane;

    const float REVC = 0.07957747154594767f;

    for (int i = tid; i < 1024; i += 256) sU[i] = ws[WS_U + i];
    if (tid < 16) ((float*)qpartS)[tid] = 0.f;

    // ---- xq projection for this batch (replaces xq_kernel) ----
    {
        int gq = tid >> 5, jj = tid & 31;
        const float4* wsx = (const float4*)(ws + WS_WXQ + gq * 512 + jj * 16);
        float4 wq0 = wsx[0], wq1 = wsx[1], wq2 = wsx[2], wq3 = wsx[3];
        float bq = ws[WS_BQ + gq];
        for (int t2 = 0; t2 < T_STEPS; ++t2) {
            const float4* row = (const float4*)(inputs + (t2 * 64 + b) * 512 + jj * 16);
            float4 x0 = row[0], x1 = row[1], x2 = row[2], x3 = row[3];
            float acc = x0.x*wq0.x + x0.y*wq0.y + x0.z*wq0.z + x0.w*wq0.w
                      + x1.x*wq1.x + x1.y*wq1.y + x1.z*wq1.z + x1.w*wq1.w
                      + x2.x*wq2.x + x2.y*wq2.y + x2.z*wq2.z + x2.w*wq2.w
                      + x3.x*wq3.x + x3.y*wq3.y + x3.z*wq3.z + x3.w*wq3.w;
            acc += __shfl_xor(acc, 1);  acc += __shfl_xor(acc, 2);
            acc += __shfl_xor(acc, 4);  acc += __shfl_xor(acc, 8);
            acc += __shfl_xor(acc, 16);
            if (jj == 0) sXq[t2 * 8 + gq] = (acc + bq) * REVC;   // pre-scaled
        }
    }

    // register-resident weights
    v2f wha2[4], whb2[4];
    #pragma unroll
    for (int j = 0; j < 4; ++j) {
        wha2[j] = mkv(ws[WS_WHQ + (2*j) * 512 + tid],       ws[WS_WHQ + (2*j+1) * 512 + tid]);
        whb2[j] = mkv(ws[WS_WHQ + (2*j) * 512 + tid + 256], ws[WS_WHQ + (2*j+1) * 512 + tid + 256]);
    }
    v2f w2hp[8];
    {
        float4 a0 = *(const float4*)&W_q2h[tid * 8];
        float4 a1 = *(const float4*)&W_q2h[tid * 8 + 4];
        float4 b0 = *(const float4*)&W_q2h[(tid + 256) * 8];
        float4 b1 = *(const float4*)&W_q2h[(tid + 256) * 8 + 4];
        w2hp[0] = mkv(a0.x, b0.x); w2hp[1] = mkv(a0.y, b0.y);
        w2hp[2] = mkv(a0.z, b0.z); w2hp[3] = mkv(a0.w, b0.w);
        w2hp[4] = mkv(a1.x, b1.x); w2hp[5] = mkv(a1.y, b1.y);
        w2hp[6] = mkv(a1.z, b1.z); w2hp[7] = mkv(a1.w, b1.w);
    }

    // MFMA fragment constants (A^T in B-op layout; B in A-op layout), f16
    half4v ArT[2], AiT[2], nAiT[2], Brf[2], Bif[2], nBif[2];
    {
        int q4 = lane >> 4, n = lane & 15;
        #pragma unroll
        for (int gl = 0; gl < 2; ++gl) {
            const float* Ab = ws + WS_AB + (wv * 2 + gl) * 1024;
            const float* Bb = Ab + 512;
            #pragma unroll
            for (int j = 0; j < 4; ++j) {
                int k = 4 * q4 + j;
                float ar = Ab[(n * 16 + k) * 2], ai = Ab[(n * 16 + k) * 2 + 1];
                float br = Bb[(n * 16 + k) * 2], bi = Bb[(n * 16 + k) * 2 + 1];
                ArT[gl][j]  = (__fp16)ar;  AiT[gl][j] = (__fp16)ai;  nAiT[gl][j] = (__fp16)(-ai);
                Brf[gl][j]  = (__fp16)br;  Bif[gl][j] = (__fp16)bi;  nBif[gl][j] = (__fp16)(-bi);
            }
        }
    }

    __syncthreads();

    // d0-build constants. State j bits: j = (4*(lane>>4)+e)*16 + (lane&15); Gray m = j^(j>>1):
    // m7=L5 m6=L5^L4 m5=L4^e1 m4=e1^e0 m3=e0^L3 m2=L3^L2 m1=L2^L1 m0=L1^L0
    v2f sA0[2], sB0[2], sA1[2], sB1[2], sA5[2], sB5[2], sA6[2], sB6[2], sA7[2], sB7[2];
    v2f A2a[2], B2a[2], A2b[2], B2b[2];
    v2f A3a[2], B3a[2], A3b[2], B3b[2];
    v2f A4a[2], B4a[2], A4b[2], B4b[2];
    {
        int s0 = (l >> 5) & 1;
        int s1 = ((l >> 5) ^ (l >> 4)) & 1;
        int s5 = ((l >> 3) ^ (l >> 2)) & 1;
        int s6 = ((l >> 2) ^ (l >> 1)) & 1;
        int s7 = ((l >> 1) ^ l) & 1;
        int L4 = (l >> 4) & 1;
        int L3 = (l >> 3) & 1;
        #pragma unroll
        for (int gl = 0; gl < 2; ++gl) {
            const float* d0 = sU + (wv * 32 + gl * 16) * 8;
            #define CA(q,c) mkv(d0[(q)*8 + (c)*4 + 0], d0[(q)*8 + (c)*4 + 1])
            #define CB(q,c) mkv(d0[(q)*8 + (c)*4 + 3], -d0[(q)*8 + (c)*4 + 2])
            sA0[gl] = s0 ? CA(0,1) : CA(0,0);  sB0[gl] = s0 ? CB(0,1) : CB(0,0);
            sA1[gl] = s1 ? CA(1,1) : CA(1,0);  sB1[gl] = s1 ? CB(1,1) : CB(1,0);
            sA5[gl] = s5 ? CA(5,1) : CA(5,0);  sB5[gl] = s5 ? CB(5,1) : CB(5,0);
            sA6[gl] = s6 ? CA(6,1) : CA(6,0);  sB6[gl] = s6 ? CB(6,1) : CB(6,0);
            sA7[gl] = s7 ? CA(7,1) : CA(7,0);  sB7[gl] = s7 ? CB(7,1) : CB(7,0);
            A2a[gl] = L4 ? CA(2,1) : CA(2,0);  B2a[gl] = L4 ? CB(2,1) : CB(2,0);
            A2b[gl] = L4 ? CA(2,0) : CA(2,1);  B2b[gl] = L4 ? CB(2,0) : CB(2,1);
            A3a[gl] = CA(3,0);                 B3a[gl] = CB(3,0);
            A3b[gl] = CA(3,1);                 B3b[gl] = CB(3,1);
            A4a[gl] = L3 ? CA(4,1) : CA(4,0);  B4a[gl] = L3 ? CB(4,1) : CB(4,0);
            A4b[gl] = L3 ? CA(4,0) : CA(4,1);  B4b[gl] = L3 ? CB(4,0) : CB(4,1);
            #undef CA
            #undef CB
        }
    }

    // e-extraction constants (see round-4 derivation). SHsgnR pre-folds REVC for gl=0.
    half4v Bsgn; f32x4 SHsgn, SHsgnR;
    {
        int q = lane & 15;
        int g4 = lane >> 4;
        int mlo = (q < 4) ? 0 : (q == 4) ? 8 : (q == 5) ? 12 : (q == 6) ? 14 : (q == 7) ? 15 : 0;
        int mhi = (q == 0) ? 8 : (q == 1) ? 12 : (q == 2) ? 14 : 15;
        #pragma unroll
        for (int j = 0; j < 4; ++j) {
            int k = 4 * g4 + j;
            float bs = (q < 8) ? ((__builtin_popcount(k & mlo) & 1) ? -1.f : 1.f) : 0.f;
            Bsgn[j] = (__fp16)bs;
            SHsgn[j]  = (__builtin_popcount(k & mhi) & 1) ? -1.f : 1.f;
            SHsgnR[j] = SHsgn[j] * REVC;
        }
    }

    const f32x4 zacc = {0.f, 0.f, 0.f, 0.f};
    float c0 = 0.f, c1 = 0.f, h0 = 0.f, h1 = 0.f;

    // prefetched xq for step t
    float4 xqa = *(const float4*)&sXq[0];
    float4 xqb = *(const float4*)&sXq[4];

    // ================= recurrence =================
    for (int t = 0; t < T_STEPS; ++t) {
        int p = t & 1;
        float ang[8];
        {
            float4 qa = *(const float4*)&qpartS[p][0];
            float4 qb = *(const float4*)&qpartS[p][4];
            ang[0] = qa.x + xqa.x; ang[1] = qa.y + xqa.y;
            ang[2] = qa.z + xqa.z; ang[3] = qa.w + xqa.w;
            ang[4] = qb.x + xqb.x; ang[5] = qb.y + xqb.y;
            ang[6] = qb.z + xqb.z; ang[7] = qb.w + xqb.w;
        }

        float e[8];
        #pragma unroll
        for (int gl = 0; gl < 2; ++gl) {
            float sh[8], ch[8];
            #pragma unroll
            for (int q = 0; q < 8; ++q) fsincos(ang[q], &sh[q], &ch[q]);

            // selected d0 columns
            v2f u0 = ch[0] * sA0[gl] + sh[0] * sB0[gl];
            v2f u1 = ch[1] * sA1[gl] + sh[1] * sB1[gl];
            v2f u5 = ch[5] * sA5[gl] + sh[5] * sB5[gl];
            v2f u6 = ch[6] * sA6[gl] + sh[6] * sB6[gl];
            v2f u7 = ch[7] * sA7[gl] + sh[7] * sB7[gl];
            v2f u2a = ch[2] * A2a[gl] + sh[2] * B2a[gl];
            v2f u2b = ch[2] * A2b[gl] + sh[2] * B2b[gl];
            v2f u3a = ch[3] * A3a[gl] + sh[3] * B3a[gl];
            v2f u3b = ch[3] * A3b[gl] + sh[3] * B3b[gl];
            v2f u4a = ch[4] * A4a[gl] + sh[4] * B4a[gl];
            v2f u4b = ch[4] * A4b[gl] + sh[4] * B4b[gl];

            // 13-cmulv tree
            v2f hi = cmulv(u0, u1);
            v2f lo = cmulv(cmulv(u5, u6), u7);
            v2f hilo = cmulv(hi, lo);
            v2f hl_a = cmulv(hilo, u4a);
            v2f hl_b = cmulv(hilo, u4b);
            v2f u23_0 = cmulv(u2a, u3a);
            v2f u23_1 = cmulv(u2a, u3b);
            v2f u23_2 = cmulv(u2b, u3b);
            v2f u23_3 = cmulv(u2b, u3a);
            v2f a0 = cmulv(u23_0, hl_a);
            v2f a1 = cmulv(u23_1, hl_b);
            v2f a2 = cmulv(u23_2, hl_a);
            v2f a3 = cmulv(u23_3, hl_b);

            half4v Sr = pk4(a0.x, a1.x, a2.x, a3.x);
            half4v Si = pk4(a0.y, a1.y, a2.y, a3.y);

            // T^T = S^T A^T (complex, chained accumulators)
            f32x4 TrT = __builtin_amdgcn_mfma_f32_16x16x16f16(Sr, ArT[gl], zacc, 0, 0, 0);
            TrT = __builtin_amdgcn_mfma_f32_16x16x16f16(Si, nAiT[gl], TrT, 0, 0, 0);
            f32x4 TiT = __builtin_amdgcn_mfma_f32_16x16x16f16(Sr, AiT[gl], zacc, 0, 0, 0);
            TiT = __builtin_amdgcn_mfma_f32_16x16x16f16(Si, ArT[gl], TiT, 0, 0, 0);
            half4v TrH = pk4(TrT[0], TrT[1], TrT[2], TrT[3]);
            half4v TiH = pk4(TiT[0], TiT[1], TiT[2], TiT[3]);
            // S'^T = B T^T (complex, chained)
            f32x4 Xr = __builtin_amdgcn_mfma_f32_16x16x16f16(Brf[gl], TrH, zacc, 0, 0, 0);
            Xr = __builtin_amdgcn_mfma_f32_16x16x16f16(nBif[gl], TiH, Xr, 0, 0, 0);
            f32x4 Xi = __builtin_amdgcn_mfma_f32_16x16x16f16(Brf[gl], TiH, zacc, 0, 0, 0);
            Xi = __builtin_amdgcn_mfma_f32_16x16x16f16(Bif[gl], TrH, Xi, 0, 0, 0);

            // probs → e-extraction via one MFMA
            f32x4 P = Xr * Xr + Xi * Xi;
            half4v Pf = pk4(P[0], P[1], P[2], P[3]);
            f32x4 Cm = __builtin_amdgcn_mfma_f32_16x16x16f16(Pf, Bsgn, zacc, 0, 0, 0);
            f32x4 Mm = Cm * ((gl == 0) ? SHsgnR : SHsgn);
            float v = (Mm[0] + Mm[1]) + (Mm[2] + Mm[3]);
            v += swap16(v, lane);
            v += swap32(v, lane);
            e[0] = rdl(v, 0); e[1] = rdl(v, 1); e[2] = rdl(v, 2); e[3] = rdl(v, 3);
            e[4] = rdl(v, 4); e[5] = rdl(v, 5); e[6] = rdl(v, 6); e[7] = rdl(v, 7);
            if (gl == 0) {
                #pragma unroll
                for (int q = 0; q < 8; ++q) ang[q] = e[q];   // pre-scaled via SHsgnR
            }
        }
        if (lane == 0) {
            float4 e0v; e0v.x = e[0]; e0v.y = e[1]; e0v.z = e[2]; e0v.w = e[3];
            float4 e1v; e1v.x = e[4]; e1v.y = e[5]; e1v.z = e[6]; e1v.w = e[7];
            *(float4*)&sexpW[wv][0] = e0v;
            *(float4*)&sexpW[wv][4] = e1v;
        }
        __syncthreads();

        // zero the buffer just read (all waves provably past the read via the barrier);
        // prefetch next step's xq (sXq is static)
        if (tid < 8) qpartS[p][tid] = 0.f;
        if (t + 1 < T_STEPS) {
            xqa = *(const float4*)&sXq[(t + 1) * 8];
            xqb = *(const float4*)&sXq[(t + 1) * 8 + 4];
        }

        // ---- LSTM cell ----
        {
            v2f pre[4];
            #pragma unroll
            for (int g = 0; g < 4; ++g) {
                float4 ea = *(const float4*)&sexpW[g][0];
                float4 eb2 = *(const float4*)&sexpW[g][4];
                v2f acc = ea.x * w2hp[0] + ea.y * w2hp[1] + ea.z * w2hp[2] + ea.w * w2hp[3]
                        + eb2.x * w2hp[4] + eb2.y * w2hp[5] + eb2.z * w2hp[6] + eb2.w * w2hp[7];
                pre[g] = acc;
            }
            float f0 = fast_sigmoid(pre[0].x), i0 = fast_sigmoid(pre[1].x);
            float g0 = fast_tanh(pre[2].x),    o0 = fast_sigmoid(pre[3].x);
            c0 = f0 * c0 + i0 * g0;  h0 = o0 * fast_tanh(c0);
            float f1 = fast_sigmoid(pre[0].y), i1 = fast_sigmoid(pre[1].y);
            float g1 = fast_tanh(pre[2].y),    o1 = fast_sigmoid(pre[3].y);
            c1 = f1 * c1 + i1 * g1;  h1 = o1 * fast_tanh(c1);
            // direct per-step h-history store
            out[(t * 64 + b) * 512 + tid]       = h0;
            out[(t * 64 + b) * 512 + tid + 256] = h1;
        }

        // ---- qpart for next step: wave partials via LDS float atomics ----
        {
            v2f pp[4];
            #pragma unroll
            for (int j = 0; j < 4; ++j) pp[j] = wha2[j] * h0 + whb2[j] * h1;
            #pragma unroll
            for (int j = 0; j < 4; ++j) {
                pp[j] += mkv(lanexor<1>(pp[j].x, lane), lanexor<1>(pp[j].y, lane));
                pp[j] += mkv(lanexor<2>(pp[j].x, lane), lanexor<2>(pp[j].y, lane));
                pp[j] += mkv(lanexor<4>(pp[j].x, lane), lanexor<4>(pp[j].y, lane));
            }
            int sel = lane & 7;
            float y = (sel == 0) ? pp[0].x : (sel == 1) ? pp[0].y
                    : (sel == 2) ? pp[1].x : (sel == 3) ? pp[1].y
                    : (sel == 4) ? pp[2].x : (sel == 5) ? pp[2].y
                    : (sel == 6) ? pp[3].x : pp[3].y;
            y += lanexor<8>(y, lane);
            y += swap16(y, lane);
            y += swap32(y, lane);
            if (lane < 8) atomicAdd(&qpartS[p ^ 1][lane], y * REVC);
        }
        __syncthreads();
    }

    float* hx_out = out + (size_t)T_STEPS * 64 * 512;
    float* cx_out = hx_out + 64 * 512;
    hx_out[b * 512 + tid]       = h0;
    hx_out[b * 512 + tid + 256] = h1;
    cx_out[b * 512 + tid]       = c0;
    cx_out[b * 512 + tid + 256] = c1;
}

extern "C" void kernel_launch(void* const* d_in, const int* in_sizes, int n_in,
                              void* d_out, int out_size, void* d_ws, size_t ws_size,
                              hipStream_t stream)
{
    const float* inputs = (const float*)d_in[0];
    const float* W_proj = (const float*)d_in[1];
    const float* b_proj = (const float*)d_in[2];
    const float* W_toq  = (const float*)d_in[3];
    const float* W_q2h  = (const float*)d_in[4];
    const float* fP     = (const float*)d_in[5];
    const float* iP     = (const float*)d_in[6];
    const float* gP     = (const float*)d_in[7];
    const float* oP     = (const float*)d_in[8];
    float* ws  = (float*)d_ws;
    float* out = (float*)d_out;

    precompute_kernel<<<41, 256, 0, stream>>>(W_proj, b_proj, W_toq, fP, iP, gP, oP, ws);
    recurrence_kernel<<<BATCH, 256, 0, stream>>>(inputs, W_q2h, ws, out);
}

// Round 7
// 134.275 us; speedup vs baseline: 1.1298x; 1.1298x over previous
//
#include <hip/hip_runtime.h>
#include <math.h>

#define T_STEPS 32
#define BATCH 64

// ws layout (floats)
#define WS_WXQ 0        // [8][512]
#define WS_WHQ 4096     // [8][512]
#define WS_BQ  8192     // [8]
#define WS_U   8208     // 128 matrices * 8 floats (id = wv*32 + gl*16 + d*8 + w)
#define WS_XQ  9232     // [32*64][8]  (pre-scaled by REVC)
#define WS_AB  25616    // 8 combos * (A 256 cplx + B 256 cplx) = 8*1024 floats

typedef float v2f __attribute__((ext_vector_type(2)));
typedef unsigned int u32x2 __attribute__((ext_vector_type(2)));
typedef __fp16 half2v __attribute__((ext_vector_type(2)));
typedef __fp16 half4v __attribute__((ext_vector_type(4)));
typedef float f32x4 __attribute__((ext_vector_type(4)));

struct c32 { float x, y; };
__device__ __forceinline__ c32 cmul(c32 a, c32 b){ return {a.x*b.x - a.y*b.y, a.x*b.y + a.y*b.x}; }
__device__ __forceinline__ c32 cadd(c32 a, c32 b){ return {a.x+b.x, a.y+b.y}; }

__device__ __forceinline__ v2f mkv(float x, float y){ v2f r; r.x = x; r.y = y; return r; }
__device__ __forceinline__ v2f cmulv(v2f a, v2f b){
    return mkv(a.x, a.x) * b + mkv(-a.y, a.y) * mkv(b.y, b.x);
}
__device__ __forceinline__ float fast_sigmoid(float x){ return 1.f/(1.f + __expf(-x)); }
__device__ __forceinline__ float fast_tanh(float x){ float e = __expf(2.f*x); return 1.f - 2.f/(e+1.f); }

__device__ __forceinline__ half4v pk4(float a, float b, float c, float d){
#if __has_builtin(__builtin_amdgcn_cvt_pkrtz)
    half2v lo = __builtin_amdgcn_cvt_pkrtz(a, b);
    half2v hi = __builtin_amdgcn_cvt_pkrtz(c, d);
    return __builtin_shufflevector(lo, hi, 0, 1, 2, 3);
#else
    half4v r; r[0] = (__fp16)a; r[1] = (__fp16)b; r[2] = (__fp16)c; r[3] = (__fp16)d;
    return r;
#endif
}

template<int C> __device__ __forceinline__ float dppf(float v){
    return __int_as_float(__builtin_amdgcn_mov_dpp(__float_as_int(v), C, 0xF, 0xF, true));
}
__device__ __forceinline__ float swap16(float v, int lane){
#if __has_builtin(__builtin_amdgcn_permlane16_swap)
    u32x2 r = __builtin_amdgcn_permlane16_swap(__float_as_uint(v), __float_as_uint(v), false, false);
    return __uint_as_float((lane & 16) ? r.x : r.y);
#else
    return __shfl_xor(v, 16);
#endif
}
__device__ __forceinline__ float swap32(float v, int lane){
#if __has_builtin(__builtin_amdgcn_permlane32_swap)
    u32x2 r = __builtin_amdgcn_permlane32_swap(__float_as_uint(v), __float_as_uint(v), false, false);
    return __uint_as_float((lane & 32) ? r.x : r.y);
#else
    return __shfl_xor(v, 32);
#endif
}
template<int LM> __device__ __forceinline__ float lanexor(float v, int lane){
    if constexpr (LM == 1)       return dppf<0xB1>(v);
    else if constexpr (LM == 2)  return dppf<0x4E>(v);
    else if constexpr (LM == 4)  return dppf<0x1B>(dppf<0x141>(v));
    else if constexpr (LM == 8)  return dppf<0x128>(v);
    else if constexpr (LM == 16) return swap16(v, lane);
    else                         return swap32(v, lane);
}
__device__ __forceinline__ float rdl(float v, int l){
    return __int_as_float(__builtin_amdgcn_readlane(__float_as_int(v), l));
}
__device__ __forceinline__ void fsincos(float rev, float* s, float* c){
#if __has_builtin(__builtin_amdgcn_sinf) && __has_builtin(__builtin_amdgcn_cosf)
    *s = __builtin_amdgcn_sinf(rev);
    *c = __builtin_amdgcn_cosf(rev);
#else
    __sincosf(rev * 6.2831853071795864f, s, c);
#endif
}

__device__ __forceinline__ void rot_u(const float* p3, float* dst){
    float a = 0.5f * p3[0], b = 0.5f * p3[1], c = 0.5f * p3[2];
    float ca = cosf(a), sa = sinf(a);
    float cb = cosf(b), sb = sinf(b);
    float cc = cosf(c), sc = sinf(c);
    c32 eb  = {cb, -sb};
    c32 ebc = {cb,  sb};
    c32 scx = {0.f, -sc};
    c32 m00 = { eb.x * ca,  eb.y * ca};
    c32 m01 = {-eb.x * sa, -eb.y * sa};
    c32 m10 = { ebc.x * sa, ebc.y * sa};
    c32 m11 = { ebc.x * ca, ebc.y * ca};
    c32 U00 = cadd(c32{cc * m00.x, cc * m00.y}, cmul(scx, m10));
    c32 U01 = cadd(c32{cc * m01.x, cc * m01.y}, cmul(scx, m11));
    c32 U10 = cadd(cmul(scx, m00), c32{cc * m10.x, cc * m10.y});
    c32 U11 = cadd(cmul(scx, m01), c32{cc * m11.x, cc * m11.y});
    dst[0] = U00.x; dst[1] = U00.y; dst[2] = U01.x; dst[3] = U01.y;
    dst[4] = U10.x; dst[5] = U10.y; dst[6] = U11.x; dst[7] = U11.y;
}

// blocks 0..31: Wxq/Whq fold; block 32: U matrices; blocks 33..40: Kronecker A/B
__global__ void precompute_kernel(const float* __restrict__ W_proj,
                                  const float* __restrict__ b_proj,
                                  const float* __restrict__ W_toq,
                                  const float* __restrict__ fP, const float* __restrict__ iP,
                                  const float* __restrict__ gP, const float* __restrict__ oP,
                                  float* __restrict__ ws)
{
    int tid = threadIdx.x;
    int blk = blockIdx.x;
    if (blk < 32) {
        int idx = blk * 256 + tid;
        int q = idx >> 10, dd = idx & 1023;
        float acc = 0.f;
        for (int p = 0; p < 64; ++p) acc += W_toq[q * 64 + p] * W_proj[p * 1024 + dd];
        if (dd < 512) ws[WS_WXQ + q * 512 + dd] = acc;
        else          ws[WS_WHQ + q * 512 + (dd - 512)] = acc;
        if (idx < 8) {
            float a2 = 0.f;
            for (int p = 0; p < 64; ++p) a2 += W_toq[idx * 64 + p] * b_proj[p];
            ws[WS_BQ + idx] = a2;
        }
    } else if (blk == 32) {
        if (tid < 128) {
            int gt = tid >> 5, rest = tid & 31;
            const float* P = (gt == 0) ? fP : (gt == 1) ? iP : (gt == 2) ? gP : oP;
            int g = (rest >> 4) & 1, d = (rest >> 3) & 1, w = rest & 7;
            rot_u(P + (((g * 2 + d) * 8 + w) * 3), ws + WS_U + tid * 8);
        }
    } else {
        // Kronecker pair matrices for combo = (gt*2+gl)
        __shared__ float sW[8][8];
        int combo = blk - 33;
        int gt = combo >> 1, gl = combo & 1;
        if (tid < 8) {
            const float* P = (gt == 0) ? fP : (gt == 1) ? iP : (gt == 2) ? gP : oP;
            rot_u(P + (((gl * 2 + 1) * 8 + tid) * 3), &sW[tid][0]);  // d=1, wire tid
        }
        __syncthreads();
        int rp = tid >> 4, rr = tid & 15;
        c32 pa = {1.f, 0.f};
        #pragma unroll
        for (int w = 0; w < 4; ++w) {
            int i = (rp >> (3 - w)) & 1, j = (rr >> (3 - w)) & 1;
            c32 e = {sW[w][(i * 2 + j) * 2], sW[w][(i * 2 + j) * 2 + 1]};
            pa = cmul(pa, e);
        }
        ws[WS_AB + combo * 1024 + tid * 2]     = pa.x;
        ws[WS_AB + combo * 1024 + tid * 2 + 1] = pa.y;
        c32 pb = {1.f, 0.f};
        #pragma unroll
        for (int w = 4; w < 8; ++w) {
            int i = (rp >> (7 - w)) & 1, j = (rr >> (7 - w)) & 1;
            c32 e = {sW[w][(i * 2 + j) * 2], sW[w][(i * 2 + j) * 2 + 1]};
            pb = cmul(pb, e);
        }
        ws[WS_AB + combo * 1024 + 512 + tid * 2]     = pb.x;
        ws[WS_AB + combo * 1024 + 512 + tid * 2 + 1] = pb.y;
    }
}

__global__ void xq_kernel(const float* __restrict__ inputs, float* __restrict__ ws)
{
    __shared__ float xs[512];
    int row = blockIdx.x;           // t*64 + b
    int tid = threadIdx.x;          // 256
    xs[tid]       = inputs[row * 512 + tid];
    xs[tid + 256] = inputs[row * 512 + 256 + tid];
    __syncthreads();
    int g = tid >> 5, j = tid & 31;
    const float* w = ws + WS_WXQ + g * 512;
    float acc = 0.f;
    #pragma unroll 4
    for (int i = 0; i < 16; ++i) acc += xs[j + 32 * i] * w[j + 32 * i];
    acc += __shfl_xor(acc, 1);  acc += __shfl_xor(acc, 2);
    acc += __shfl_xor(acc, 4);  acc += __shfl_xor(acc, 8);
    acc += __shfl_xor(acc, 16);
    // pre-scaled by REVC: sXq feeds only the angle sum
    if (j == 0) ws[WS_XQ + row * 8 + g] = (acc + ws[WS_BQ + g]) * 0.07957747154594767f;
}

__global__ __launch_bounds__(256, 1)
void recurrence_kernel(const float* __restrict__ W_q2h,
                       const float* __restrict__ ws,
                       float* __restrict__ out)
{
    __shared__ __align__(16) float sU[1024];
    __shared__ __align__(16) float sXq[T_STEPS * 8];
    __shared__ __align__(16) float sexpW[4][8];
    __shared__ __align__(16) float qpartW[4][8];

    int tid = threadIdx.x;   // 256
    int b   = blockIdx.x;    // 64
    int wv  = tid >> 6;
    int lane = tid & 63;
    int l = lane;

    for (int i = tid; i < 1024; i += 256) sU[i] = ws[WS_U + i];
    sXq[tid] = ws[WS_XQ + ((tid >> 3) * 64 + b) * 8 + (tid & 7)];
    if (tid < 32) ((float*)qpartW)[tid] = 0.f;

    // register-resident weights
    v2f wha2[4], whb2[4];
    #pragma unroll
    for (int j = 0; j < 4; ++j) {
        wha2[j] = mkv(ws[WS_WHQ + (2*j) * 512 + tid],       ws[WS_WHQ + (2*j+1) * 512 + tid]);
        whb2[j] = mkv(ws[WS_WHQ + (2*j) * 512 + tid + 256], ws[WS_WHQ + (2*j+1) * 512 + tid + 256]);
    }
    v2f w2hp[8];
    {
        float4 a0 = *(const float4*)&W_q2h[tid * 8];
        float4 a1 = *(const float4*)&W_q2h[tid * 8 + 4];
        float4 b0 = *(const float4*)&W_q2h[(tid + 256) * 8];
        float4 b1 = *(const float4*)&W_q2h[(tid + 256) * 8 + 4];
        w2hp[0] = mkv(a0.x, b0.x); w2hp[1] = mkv(a0.y, b0.y);
        w2hp[2] = mkv(a0.z, b0.z); w2hp[3] = mkv(a0.w, b0.w);
        w2hp[4] = mkv(a1.x, b1.x); w2hp[5] = mkv(a1.y, b1.y);
        w2hp[6] = mkv(a1.z, b1.z); w2hp[7] = mkv(a1.w, b1.w);
    }

    // MFMA fragment constants (A^T in B-op layout; B in A-op layout), f16
    half4v ArT[2], AiT[2], nAiT[2], Brf[2], Bif[2], nBif[2];
    {
        int q4 = lane >> 4, n = lane & 15;
        #pragma unroll
        for (int gl = 0; gl < 2; ++gl) {
            const float* Ab = ws + WS_AB + (wv * 2 + gl) * 1024;
            const float* Bb = Ab + 512;
            #pragma unroll
            for (int j = 0; j < 4; ++j) {
                int k = 4 * q4 + j;
                float ar = Ab[(n * 16 + k) * 2], ai = Ab[(n * 16 + k) * 2 + 1];
                float br = Bb[(n * 16 + k) * 2], bi = Bb[(n * 16 + k) * 2 + 1];
                ArT[gl][j]  = (__fp16)ar;  AiT[gl][j] = (__fp16)ai;  nAiT[gl][j] = (__fp16)(-ai);
                Brf[gl][j]  = (__fp16)br;  Bif[gl][j] = (__fp16)bi;  nBif[gl][j] = (__fp16)(-bi);
            }
        }
    }

    __syncthreads();

    // d0-build constants. State j bits: j = (4*(lane>>4)+e)*16 + (lane&15); Gray m = j^(j>>1):
    // m7=L5 m6=L5^L4 m5=L4^e1 m4=e1^e0 m3=e0^L3 m2=L3^L2 m1=L2^L1 m0=L1^L0
    v2f sA0[2], sB0[2], sA1[2], sB1[2], sA5[2], sB5[2], sA6[2], sB6[2], sA7[2], sB7[2];
    v2f A2a[2], B2a[2], A2b[2], B2b[2];
    v2f A3a[2], B3a[2], A3b[2], B3b[2];
    v2f A4a[2], B4a[2], A4b[2], B4b[2];
    {
        int s0 = (l >> 5) & 1;
        int s1 = ((l >> 5) ^ (l >> 4)) & 1;
        int s5 = ((l >> 3) ^ (l >> 2)) & 1;
        int s6 = ((l >> 2) ^ (l >> 1)) & 1;
        int s7 = ((l >> 1) ^ l) & 1;
        int L4 = (l >> 4) & 1;
        int L3 = (l >> 3) & 1;
        #pragma unroll
        for (int gl = 0; gl < 2; ++gl) {
            const float* d0 = sU + (wv * 32 + gl * 16) * 8;
            #define CA(q,c) mkv(d0[(q)*8 + (c)*4 + 0], d0[(q)*8 + (c)*4 + 1])
            #define CB(q,c) mkv(d0[(q)*8 + (c)*4 + 3], -d0[(q)*8 + (c)*4 + 2])
            sA0[gl] = s0 ? CA(0,1) : CA(0,0);  sB0[gl] = s0 ? CB(0,1) : CB(0,0);
            sA1[gl] = s1 ? CA(1,1) : CA(1,0);  sB1[gl] = s1 ? CB(1,1) : CB(1,0);
            sA5[gl] = s5 ? CA(5,1) : CA(5,0);  sB5[gl] = s5 ? CB(5,1) : CB(5,0);
            sA6[gl] = s6 ? CA(6,1) : CA(6,0);  sB6[gl] = s6 ? CB(6,1) : CB(6,0);
            sA7[gl] = s7 ? CA(7,1) : CA(7,0);  sB7[gl] = s7 ? CB(7,1) : CB(7,0);
            A2a[gl] = L4 ? CA(2,1) : CA(2,0);  B2a[gl] = L4 ? CB(2,1) : CB(2,0);
            A2b[gl] = L4 ? CA(2,0) : CA(2,1);  B2b[gl] = L4 ? CB(2,0) : CB(2,1);
            A3a[gl] = CA(3,0);                 B3a[gl] = CB(3,0);
            A3b[gl] = CA(3,1);                 B3b[gl] = CB(3,1);
            A4a[gl] = L3 ? CA(4,1) : CA(4,0);  B4a[gl] = L3 ? CB(4,1) : CB(4,0);
            A4b[gl] = L3 ? CA(4,0) : CA(4,1);  B4b[gl] = L3 ? CB(4,0) : CB(4,1);
            #undef CA
            #undef CB
        }
    }

    const float REVC = 0.07957747154594767f;

    // e-extraction constants (see round-4 derivation). SHsgnR pre-folds REVC for gl=0.
    half4v Bsgn; f32x4 SHsgn, SHsgnR;
    {
        int q = lane & 15;
        int g4 = lane >> 4;
        int mlo = (q < 4) ? 0 : (q == 4) ? 8 : (q == 5) ? 12 : (q == 6) ? 14 : (q == 7) ? 15 : 0;
        int mhi = (q == 0) ? 8 : (q == 1) ? 12 : (q == 2) ? 14 : 15;
        #pragma unroll
        for (int j = 0; j < 4; ++j) {
            int k = 4 * g4 + j;
            float bs = (q < 8) ? ((__builtin_popcount(k & mlo) & 1) ? -1.f : 1.f) : 0.f;
            Bsgn[j] = (__fp16)bs;
            SHsgn[j]  = (__builtin_popcount(k & mhi) & 1) ? -1.f : 1.f;
            SHsgnR[j] = SHsgn[j] * REVC;
        }
    }

    const f32x4 zacc = {0.f, 0.f, 0.f, 0.f};
    float c0 = 0.f, c1 = 0.f, h0 = 0.f, h1 = 0.f;
    int l7 = lane & 7;

    // ================= recurrence =================
    for (int t = 0; t < T_STEPS; ++t) {
        // per-lane angle: lane l handles qubit (l&7); LDS broadcast reads (conflict-free)
        float sl, cl;
        {
            float angl = (qpartW[0][l7] + qpartW[1][l7])
                       + (qpartW[2][l7] + qpartW[3][l7])
                       + sXq[t * 8 + l7];            // all pre-scaled by REVC
            fsincos(angl, &sl, &cl);
        }

        #pragma unroll
        for (int gl = 0; gl < 2; ++gl) {
            // broadcast the 8 cos/sin via readlane (full-rate) instead of 16 trans ops
            float ch[8], sh[8];
            #pragma unroll
            for (int q = 0; q < 8; ++q) { ch[q] = rdl(cl, q); sh[q] = rdl(sl, q); }

            // selected d0 columns
            v2f u0 = ch[0] * sA0[gl] + sh[0] * sB0[gl];
            v2f u1 = ch[1] * sA1[gl] + sh[1] * sB1[gl];
            v2f u5 = ch[5] * sA5[gl] + sh[5] * sB5[gl];
            v2f u6 = ch[6] * sA6[gl] + sh[6] * sB6[gl];
            v2f u7 = ch[7] * sA7[gl] + sh[7] * sB7[gl];
            v2f u2a = ch[2] * A2a[gl] + sh[2] * B2a[gl];
            v2f u2b = ch[2] * A2b[gl] + sh[2] * B2b[gl];
            v2f u3a = ch[3] * A3a[gl] + sh[3] * B3a[gl];
            v2f u3b = ch[3] * A3b[gl] + sh[3] * B3b[gl];
            v2f u4a = ch[4] * A4a[gl] + sh[4] * B4a[gl];
            v2f u4b = ch[4] * A4b[gl] + sh[4] * B4b[gl];

            // 13-cmulv tree
            v2f hi = cmulv(u0, u1);
            v2f lo = cmulv(cmulv(u5, u6), u7);
            v2f hilo = cmulv(hi, lo);
            v2f hl_a = cmulv(hilo, u4a);
            v2f hl_b = cmulv(hilo, u4b);
            v2f u23_0 = cmulv(u2a, u3a);
            v2f u23_1 = cmulv(u2a, u3b);
            v2f u23_2 = cmulv(u2b, u3b);
            v2f u23_3 = cmulv(u2b, u3a);
            v2f a0 = cmulv(u23_0, hl_a);
            v2f a1 = cmulv(u23_1, hl_b);
            v2f a2 = cmulv(u23_2, hl_a);
            v2f a3 = cmulv(u23_3, hl_b);

            half4v Sr = pk4(a0.x, a1.x, a2.x, a3.x);
            half4v Si = pk4(a0.y, a1.y, a2.y, a3.y);

            // T^T = S^T A^T (complex, chained accumulators)
            f32x4 TrT = __builtin_amdgcn_mfma_f32_16x16x16f16(Sr, ArT[gl], zacc, 0, 0, 0);
            TrT = __builtin_amdgcn_mfma_f32_16x16x16f16(Si, nAiT[gl], TrT, 0, 0, 0);
            f32x4 TiT = __builtin_amdgcn_mfma_f32_16x16x16f16(Sr, AiT[gl], zacc, 0, 0, 0);
            TiT = __builtin_amdgcn_mfma_f32_16x16x16f16(Si, ArT[gl], TiT, 0, 0, 0);
            half4v TrH = pk4(TrT[0], TrT[1], TrT[2], TrT[3]);
            half4v TiH = pk4(TiT[0], TiT[1], TiT[2], TiT[3]);
            // S'^T = B T^T (complex, chained)
            f32x4 Xr = __builtin_amdgcn_mfma_f32_16x16x16f16(Brf[gl], TrH, zacc, 0, 0, 0);
            Xr = __builtin_amdgcn_mfma_f32_16x16x16f16(nBif[gl], TiH, Xr, 0, 0, 0);
            f32x4 Xi = __builtin_amdgcn_mfma_f32_16x16x16f16(Brf[gl], TiH, zacc, 0, 0, 0);
            Xi = __builtin_amdgcn_mfma_f32_16x16x16f16(Bif[gl], TrH, Xi, 0, 0, 0);

            // probs → e-extraction via one MFMA; v on lane l = e[l&15]
            f32x4 P = Xr * Xr + Xi * Xi;
            half4v Pf = pk4(P[0], P[1], P[2], P[3]);
            f32x4 Cm = __builtin_amdgcn_mfma_f32_16x16x16f16(Pf, Bsgn, zacc, 0, 0, 0);
            f32x4 Mm = Cm * ((gl == 0) ? SHsgnR : SHsgn);
            float v = (Mm[0] + Mm[1]) + (Mm[2] + Mm[3]);
            v += swap16(v, lane);
            v += swap32(v, lane);
            if (gl == 0) {
                fsincos(v, &sl, &cl);       // pre-scaled via SHsgnR; feeds gl=1 broadcast
            } else {
                if (lane < 8) sexpW[wv][lane] = v;   // raw e for LSTM
            }
        }
        __syncthreads();

        // ---- LSTM cell ----
        {
            v2f pre[4];
            #pragma unroll
            for (int g = 0; g < 4; ++g) {
                float4 ea = *(const float4*)&sexpW[g][0];
                float4 eb2 = *(const float4*)&sexpW[g][4];
                v2f acc = ea.x * w2hp[0] + ea.y * w2hp[1] + ea.z * w2hp[2] + ea.w * w2hp[3]
                        + eb2.x * w2hp[4] + eb2.y * w2hp[5] + eb2.z * w2hp[6] + eb2.w * w2hp[7];
                pre[g] = acc;
            }
            float f0 = fast_sigmoid(pre[0].x), i0 = fast_sigmoid(pre[1].x);
            float g0 = fast_tanh(pre[2].x),    o0 = fast_sigmoid(pre[3].x);
            c0 = f0 * c0 + i0 * g0;  h0 = o0 * fast_tanh(c0);
            float f1 = fast_sigmoid(pre[0].y), i1 = fast_sigmoid(pre[1].y);
            float g1 = fast_tanh(pre[2].y),    o1 = fast_sigmoid(pre[3].y);
            c1 = f1 * c1 + i1 * g1;  h1 = o1 * fast_tanh(c1);
            // direct per-step h-history store
            out[(t * 64 + b) * 512 + tid]       = h0;
            out[(t * 64 + b) * 512 + tid + 256] = h1;
        }

        // ---- qpart for next step (pre-scaled by REVC) ----
        {
            v2f pp[4];
            #pragma unroll
            for (int j = 0; j < 4; ++j) pp[j] = wha2[j] * h0 + whb2[j] * h1;
            #pragma unroll
            for (int j = 0; j < 4; ++j) {
                pp[j] += mkv(lanexor<1>(pp[j].x, lane), lanexor<1>(pp[j].y, lane));
                pp[j] += mkv(lanexor<2>(pp[j].x, lane), lanexor<2>(pp[j].y, lane));
                pp[j] += mkv(lanexor<4>(pp[j].x, lane), lanexor<4>(pp[j].y, lane));
            }
            int sel = lane & 7;
            float y = (sel == 0) ? pp[0].x : (sel == 1) ? pp[0].y
                    : (sel == 2) ? pp[1].x : (sel == 3) ? pp[1].y
                    : (sel == 4) ? pp[2].x : (sel == 5) ? pp[2].y
                    : (sel == 6) ? pp[3].x : pp[3].y;
            y += lanexor<8>(y, lane);
            y += swap16(y, lane);
            y += swap32(y, lane);
            if (lane < 8) qpartW[wv][lane] = y * REVC;
        }
        __syncthreads();
    }

    float* hx_out = out + (size_t)T_STEPS * 64 * 512;
    float* cx_out = hx_out + 64 * 512;
    hx_out[b * 512 + tid]       = h0;
    hx_out[b * 512 + tid + 256] = h1;
    cx_out[b * 512 + tid]       = c0;
    cx_out[b * 512 + tid + 256] = c1;
}

extern "C" void kernel_launch(void* const* d_in, const int* in_sizes, int n_in,
                              void* d_out, int out_size, void* d_ws, size_t ws_size,
                              hipStream_t stream)
{
    const float* inputs = (const float*)d_in[0];
    const float* W_proj = (const float*)d_in[1];
    const float* b_proj = (const float*)d_in[2];
    const float* W_toq  = (const float*)d_in[3];
    const float* W_q2h  = (const float*)d_in[4];
    const float* fP     = (const float*)d_in[5];
    const float* iP     = (const float*)d_in[6];
    const float* gP     = (const float*)d_in[7];
    const float* oP     = (const float*)d_in[8];
    float* ws  = (float*)d_ws;
    float* out = (float*)d_out;

    precompute_kernel<<<41, 256, 0, stream>>>(W_proj, b_proj, W_toq, fP, iP, gP, oP, ws);
    xq_kernel<<<T_STEPS * BATCH, 256, 0, stream>>>(inputs, ws);
    recurrence_kernel<<<BATCH, 256, 0, stream>>>(W_q2h, ws, out);
}